// Round 1
// baseline (133.120 us; speedup 1.0000x reference)
//
#include <hip/hip_runtime.h>
#include <hip/hip_bf16.h>
#include <math.h>

// Problem constants (from reference)
constexpr int BS = 64;
constexpr int NQ = 300;
constexpr int T  = 1280;         // BS * TGT_PER
constexpr int ROWS = BS * NQ;    // 19200
constexpr int COL4 = T / 4;      // 320 float4 per row
constexpr int TOTAL4 = ROWS * COL4;

__device__ __forceinline__ float cost_one(float pcx, float pw,
                                          float px1, float px2,
                                          float base,   // cref - prob0
                                          float tcx, float tw) {
    // L1 span cost in (cx,w)
    float cspan = fabsf(pcx - tcx) + fabsf(pw - tw);
    // GIoU in (x1,x2)
    float tx1 = tcx - 0.5f * tw;
    float tx2 = tcx + 0.5f * tw;
    float lt = fmaxf(px1, tx1);
    float rb = fminf(px2, tx2);
    float inter = fmaxf(rb - lt, 0.0f);
    float uni = pw + tw - inter;                 // area_a + area_b - inter
    float iou = inter / uni;
    float left  = fminf(px1, tx1);
    float right = fmaxf(px2, tx2);
    float enclose = fmaxf(right - left, 0.0f);
    float giou = iou - (enclose - uni) / enclose;
    // total = cspan + (-giou) + (-prob0) + cref
    return cspan - giou + base;
}

__global__ __launch_bounds__(256) void cost_matrix_kernel(
        const float* __restrict__ logits,   // [ROWS,2]
        const float* __restrict__ spans,    // [ROWS,2]
        const float* __restrict__ tgt,      // [T,2]
        const float* __restrict__ ref,      // [ROWS,2]
        float* __restrict__ out) {          // [ROWS,T]
    int idx = blockIdx.x * blockDim.x + threadIdx.x;
    if (idx >= TOTAL4) return;
    int row = idx / COL4;
    int c4  = idx - row * COL4;

    // ---- per-row constants (broadcast loads, L1-resident) ----
    float2 lg = ((const float2*)logits)[row];
    float prob0 = 1.0f / (1.0f + expf(lg.y - lg.x));   // softmax[..,0] over 2 classes

    float2 sp = ((const float2*)spans)[row];
    float pcx = sp.x, pw = sp.y;
    float px1 = pcx - 0.5f * pw;
    float px2 = pcx + 0.5f * pw;

    float2 rp = ((const float2*)ref)[row];
    float d0 = px1 - rp.x;
    float d1 = px2 - rp.y;
    float cref = sqrtf(d0 * d0 + d1 * d1);

    float base = cref - prob0;   // cost_reference + cost_class (both row-broadcast)

    // ---- 4 targets: two float4 loads from the 10KB cached table ----
    const float4* tgt4 = (const float4*)tgt;
    float4 t01 = tgt4[2 * c4];
    float4 t23 = tgt4[2 * c4 + 1];

    float4 res;
    res.x = cost_one(pcx, pw, px1, px2, base, t01.x, t01.y);
    res.y = cost_one(pcx, pw, px1, px2, base, t01.z, t01.w);
    res.z = cost_one(pcx, pw, px1, px2, base, t23.x, t23.y);
    res.w = cost_one(pcx, pw, px1, px2, base, t23.z, t23.w);

    ((float4*)out)[idx] = res;
}

extern "C" void kernel_launch(void* const* d_in, const int* in_sizes, int n_in,
                              void* d_out, int out_size, void* d_ws, size_t ws_size,
                              hipStream_t stream) {
    const float* pred_logits = (const float*)d_in[0];
    const float* pred_spans  = (const float*)d_in[1];
    const float* tgt_spans   = (const float*)d_in[2];
    const float* ref_points  = (const float*)d_in[3];
    float* out = (float*)d_out;

    constexpr int BLOCK = 256;
    int grid = (TOTAL4 + BLOCK - 1) / BLOCK;   // 24000 blocks
    cost_matrix_kernel<<<grid, BLOCK, 0, stream>>>(
        pred_logits, pred_spans, tgt_spans, ref_points, out);
}

// Round 3
// 120.221 us; speedup vs baseline: 1.1073x; 1.1073x over previous
//
#include <hip/hip_runtime.h>
#include <hip/hip_bf16.h>
#include <math.h>

// Problem constants (from reference): BS=64, NQ=300, NC=2, T=1280
constexpr int ROWS  = 19200;       // BS*NQ
constexpr int T     = 1280;
constexpr int COL4  = T / 4;       // 320 float4 per row
constexpr int TPR   = 80;          // threads per row; each thread -> 4 quads at stride 80
constexpr int TOTAL = ROWS * TPR;  // 1,536,000 threads
constexpr int BLOCK = 256;
constexpr int GRID  = TOTAL / BLOCK;  // 6000 exactly

typedef float vfloat4 __attribute__((ext_vector_type(4)));  // native vector for nontemporal builtin

__device__ __forceinline__ float cost_one(float pcx, float pw,
                                          float px1, float px2,
                                          float base,   // cref - prob0
                                          float tcx, float tw) {
    // L1 span cost in (cx,w)
    float cspan = fabsf(pcx - tcx) + fabsf(pw - tw);
    // GIoU in (x1,x2)
    float tx1 = tcx - 0.5f * tw;
    float tx2 = tcx + 0.5f * tw;
    float lt = fmaxf(px1, tx1);
    float rb = fminf(px2, tx2);
    float inter = fmaxf(rb - lt, 0.0f);
    float uni = pw + tw - inter;                 // area_a + area_b - inter
    float iou = inter * __builtin_amdgcn_rcpf(uni);
    float left  = fminf(px1, tx1);
    float right = fmaxf(px2, tx2);
    float enclose = fmaxf(right - left, 0.0f);
    float giou = iou - (enclose - uni) * __builtin_amdgcn_rcpf(enclose);
    // total = cspan + (-giou) + (-prob0) + cref
    return cspan - giou + base;
}

__global__ __launch_bounds__(BLOCK) void cost_matrix_kernel(
        const float* __restrict__ logits,   // [ROWS,2]
        const float* __restrict__ spans,    // [ROWS,2]
        const float* __restrict__ tgt,      // [T,2]
        const float* __restrict__ ref,      // [ROWS,2]
        float* __restrict__ out) {          // [ROWS,T]
    int idx = blockIdx.x * blockDim.x + threadIdx.x;   // < TOTAL exactly
    int row = idx / TPR;
    int c   = idx - row * TPR;   // base quad index in [0,80)

    // ---- per-row constants (amortized over 16 outputs) ----
    float2 lg = ((const float2*)logits)[row];
    float prob0 = 1.0f / (1.0f + expf(lg.y - lg.x));   // softmax[..,0] over 2 classes

    float2 sp = ((const float2*)spans)[row];
    float pcx = sp.x, pw = sp.y;
    float px1 = pcx - 0.5f * pw;
    float px2 = pcx + 0.5f * pw;

    float2 rp = ((const float2*)ref)[row];
    float d0 = px1 - rp.x;
    float d1 = px2 - rp.y;
    float base = sqrtf(d0 * d0 + d1 * d1) - prob0;  // cref - prob0 (row-broadcast)

    const float4* tgt4 = (const float4*)tgt;
    vfloat4* out4 = ((vfloat4*)out) + (size_t)row * COL4;

    #pragma unroll
    for (int j = 0; j < 4; ++j) {
        int q = c + j * TPR;             // quad index in [0,320)
        float4 t01 = tgt4[2 * q];
        float4 t23 = tgt4[2 * q + 1];
        vfloat4 res;
        res.x = cost_one(pcx, pw, px1, px2, base, t01.x, t01.y);
        res.y = cost_one(pcx, pw, px1, px2, base, t01.z, t01.w);
        res.z = cost_one(pcx, pw, px1, px2, base, t23.x, t23.y);
        res.w = cost_one(pcx, pw, px1, px2, base, t23.z, t23.w);
        // write-once streaming output: nontemporal hint
        __builtin_nontemporal_store(res, &out4[q]);
    }
}

extern "C" void kernel_launch(void* const* d_in, const int* in_sizes, int n_in,
                              void* d_out, int out_size, void* d_ws, size_t ws_size,
                              hipStream_t stream) {
    const float* pred_logits = (const float*)d_in[0];
    const float* pred_spans  = (const float*)d_in[1];
    const float* tgt_spans   = (const float*)d_in[2];
    const float* ref_points  = (const float*)d_in[3];
    float* out = (float*)d_out;

    cost_matrix_kernel<<<GRID, BLOCK, 0, stream>>>(
        pred_logits, pred_spans, tgt_spans, ref_points, out);
}